// Round 14
// baseline (62.577 us; speedup 1.0000x reference)
//
#include <hip/hip_runtime.h>
#include <hip/hip_bf16.h>

#define T_TOTAL 200000
#define T_PAD   200192            // 782 * 256 (padded s1 rows; tail t unused)
#define STEPF   (999.0f / 199999.0f)

typedef float v4f __attribute__((ext_vector_type(4)));

// Parameter quads {ww', ph'+0.25, C=2cos(ww*64*step), extra}, phases in
// REVOLUTIONS so sin(theta) = cos(2*pi*(fract(rev)-0.5)) (even poly):
// L0: [4n]               n<20, extra = A0       [0,80)
// L1: [80  + 4*(m*20+n)] m<25, n<20             [80,2080)
// L2: [2080 + 4*(m*25+n)] m<30, n<25            [2080,5080)
// L3: [5080 + 4m]        m<30                   [5080,5200)
__device__ float g_P[5200];
// Inter-kernel s1[m][t] buffer (padded): 25 x 200192 = 20 MB.
__device__ float g_s1[25 * T_PAD];

// sin(2*pi*rev) via even poly: cos(2*pi*h), h = fract(rev)-0.5. |err| ~= 4e-5.
__device__ __forceinline__ float sinp(float rev) {
    float g = __builtin_amdgcn_fractf(rev);
    float h = g - 0.5f;
    float u = h * h;
    float p = fmaf(45.621248f, u, -82.391040f);
    p = fmaf(p, u, 64.671616f);
    p = fmaf(p, u, -19.730960f);
    p = fmaf(p, u, 0.9999618f);
    return p;
}

__global__ void prep_kernel(
    const float* __restrict__ A0,
    const float* __restrict__ w0, const float* __restrict__ phi0,
    const float* __restrict__ wc0, const float* __restrict__ phic0,
    const float* __restrict__ w1, const float* __restrict__ phi1,
    const float* __restrict__ wc1, const float* __restrict__ phic1,
    const float* __restrict__ w2, const float* __restrict__ phi2,
    const float* __restrict__ wc2, const float* __restrict__ phic2,
    const float* __restrict__ w3, const float* __restrict__ phi3,
    const float* __restrict__ wc3, const float* __restrict__ phic3)
{
    const int tid = blockIdx.x * blockDim.x + threadIdx.x;
    const int stride = blockDim.x * gridDim.x;

    const double I2PI = 0.15915494309189535;
    const double D64  = 64.0 * 999.0 / 199999.0;   // tv-step between j's

    const double ws0 = fmax((double)wc0[0], 0.0), ps0 = fmax((double)phic0[0], 0.0);
    const double ws1 = fmax((double)wc1[0], 0.0), ps1 = fmax((double)phic1[0], 0.0);
    const double ws2 = fmax((double)wc2[0], 0.0), ps2 = fmax((double)phic2[0], 0.0);
    const double ws3 = fmax((double)wc3[0], 0.0), ps3 = fmax((double)phic3[0], 0.0);

    for (int n = tid; n < 20; n += stride) {
        double wr = fmax((double)w0[n], 0.0) + ws0;
        g_P[4 * n]     = (float)(wr * I2PI);
        g_P[4 * n + 1] = (float)((fmax((double)phi0[n], 0.0) + ps0) * I2PI + 0.25);
        g_P[4 * n + 2] = (float)(2.0 * cos(wr * D64));
        g_P[4 * n + 3] = A0[n];
    }
    for (int k = tid; k < 25 * 20; k += stride) {   // k = m*20+n
        double wr = fmax((double)w1[k], 0.0) + ws1;
        g_P[80 + 4 * k]     = (float)(wr * I2PI);
        g_P[80 + 4 * k + 1] = (float)((fmax((double)phi1[k], 0.0) + ps1) * I2PI + 0.25);
        g_P[80 + 4 * k + 2] = (float)(2.0 * cos(wr * D64));
        g_P[80 + 4 * k + 3] = 0.0f;
    }
    for (int k = tid; k < 30 * 25; k += stride) {   // k = m*25+n
        double wr = fmax((double)w2[k], 0.0) + ws2;
        g_P[2080 + 4 * k]     = (float)(wr * I2PI);
        g_P[2080 + 4 * k + 1] = (float)((fmax((double)phi2[k], 0.0) + ps2) * I2PI + 0.25);
        g_P[2080 + 4 * k + 2] = (float)(2.0 * cos(wr * D64));
        g_P[2080 + 4 * k + 3] = 0.0f;
    }
    for (int m = tid; m < 30; m += stride) {
        double wr = fmax((double)w3[m], 0.0) + ws3;
        g_P[5080 + 4 * m]     = (float)(wr * I2PI);
        g_P[5080 + 4 * m + 1] = (float)((fmax((double)phi3[m], 0.0) + ps3) * I2PI + 0.25);
        g_P[5080 + 4 * m + 2] = (float)(2.0 * cos(wr * D64));
        g_P[5080 + 4 * m + 3] = 0.0f;
    }
}

// Kernel A: layers 0+1. 782 blocks x 8 waves; block covers 256 t
// (t = tb + l + 64j, j<4/thread; j=0,1 direct poly, j=2,3 Chebyshev
// x_{j+1} = C*x_j - x_{j-1}). Wave w owns 4 m's m=min(floor(25w/8)+i,24);
// duplicated m's store IDENTICAL values (branchless idempotent stores).
// s0 staged in LDS [n][j][lane]; one barrier. Entire grid (6256 waves)
// is co-resident at 8 waves/SIMD -> zero scheduling tail.
__launch_bounds__(512, 8)
__global__ void k_l01()
{
    __shared__ float pp[2000];       // L1 quads  (8000 B)
    __shared__ float s0s[20 * 256];  // s0[n][j][lane] (20480 B)

    for (int i = threadIdx.x; i < 2000; i += 512) pp[i] = g_P[80 + i];

    const int l = threadIdx.x & 63;
    const int w = __builtin_amdgcn_readfirstlane(threadIdx.x >> 6);
    const int tb = blockIdx.x * 256;
    const float tv0 = fmaf((float)(tb + l), STEPF, 1.0f);
    const float tv1 = fmaf((float)(tb + l + 64), STEPF, 1.0f);

    // layer 0: wave w computes n = w, 8+w, min(16+w,19) (dups write same value)
    {
        const int nn0 = w, nn1 = 8 + w, nn2 = (16 + w < 20) ? 16 + w : 19;
        const int nn[3] = {nn0, nn1, nn2};
#pragma unroll
        for (int i = 0; i < 3; ++i) {
            const int n = nn[i];
            const v4f q = *(const v4f*)&g_P[4 * n];
            float x0 = q[3] * sinp(fmaf(q[0], tv0, q[1]));
            float x1 = q[3] * sinp(fmaf(q[0], tv1, q[1]));
            float x2 = fmaf(q[2], x1, -x0);
            float x3 = fmaf(q[2], x2, -x1);
            s0s[n * 256 +       l] = x0;
            s0s[n * 256 +  64 + l] = x1;
            s0s[n * 256 + 128 + l] = x2;
            s0s[n * 256 + 192 + l] = x3;
        }
    }
    __syncthreads();

    int m_[4];
#pragma unroll
    for (int i = 0; i < 4; ++i) {
        int m = (25 * w) / 8 + i;          // 0,3,6,9,12,15,18,21 + i
        m_[i] = (m > 24) ? 24 : m;
    }

    float acc[4][4] = {};
    float sum0[4] = {0.f, 0.f, 0.f, 0.f};
#pragma clang loop unroll_count(2)
    for (int n = 0; n < 20; ++n) {
        const float s00 = s0s[n * 256 +       l];
        const float s01 = s0s[n * 256 +  64 + l];
        const float s02 = s0s[n * 256 + 128 + l];
        const float s03 = s0s[n * 256 + 192 + l];
        sum0[0] += s00; sum0[1] += s01; sum0[2] += s02; sum0[3] += s03;
#pragma unroll
        for (int i = 0; i < 4; ++i) {
            const v4f q = *(const v4f*)&pp[4 * (m_[i] * 20 + n)];  // uniform b128
            float x0 = sinp(fmaf(q[0], tv0, q[1]));
            float x1 = sinp(fmaf(q[0], tv1, q[1]));
            float x2 = fmaf(q[2], x1, -x0);
            float x3 = fmaf(q[2], x2, -x1);
            acc[i][0] = fmaf(x0, s00, acc[i][0]);
            acc[i][1] = fmaf(x1, s01, acc[i][1]);
            acc[i][2] = fmaf(x2, s02, acc[i][2]);
            acc[i][3] = fmaf(x3, s03, acc[i][3]);
        }
    }
#pragma unroll
    for (int i = 0; i < 4; ++i) {
        float* __restrict__ o = &g_s1[m_[i] * T_PAD + tb];
        o[l]       = fmaf(0.5f, acc[i][0], 0.5f * sum0[0]);
        o[64 + l]  = fmaf(0.5f, acc[i][1], 0.5f * sum0[1]);
        o[128 + l] = fmaf(0.5f, acc[i][2], 0.5f * sum0[2]);
        o[192 + l] = fmaf(0.5f, acc[i][3], 0.5f * sum0[3]);
    }
}

// Kernel B: layers 2+3 fused. Same 8-wave/256-t block shape. s1 read
// DIRECTLY from global (25.6 KB tile is L1-resident; no LDS stage, like
// R12's 88%-busy kernel). Wave w owns 4 m's of 30 (exact via zero-flag
// on the duplicated slot). L3 folded per-m; 8-wave reduce via 8 KB LDS.
__launch_bounds__(512, 8)
__global__ void k_l23(float* __restrict__ out)
{
    __shared__ float pp[3120];       // L2+L3 quads (12480 B)
    __shared__ float shp[8 * 4 * 64];// partials [w][j][lane] (8192 B)

    for (int i = threadIdx.x; i < 3120; i += 512) pp[i] = g_P[2080 + i];
    __syncthreads();

    const int l = threadIdx.x & 63;
    const int w = __builtin_amdgcn_readfirstlane(threadIdx.x >> 6);
    const int tb = blockIdx.x * 256;
    const float tv0 = fmaf((float)(tb + l), STEPF, 1.0f);
    const float tv1 = fmaf((float)(tb + l + 64), STEPF, 1.0f);

    const int mS = (30 * w) / 8;           // 0,3,7,11,15,18,22,26
    const int mE = (30 * (w + 1)) / 8;     // exact upper bound
    int m_[4]; float fl[4];
#pragma unroll
    for (int i = 0; i < 4; ++i) {
        int m = mS + i;
        fl[i] = (m < mE) ? 1.0f : 0.0f;    // zero-weight duplicated slot
        m_[i] = (m > 29) ? 29 : m;
    }

    float acc[4][4] = {};
    float sum1[4] = {0.f, 0.f, 0.f, 0.f};
#pragma clang loop unroll_count(2)
    for (int n = 0; n < 25; ++n) {
        const float* __restrict__ sp = &g_s1[n * T_PAD + tb];
        const float s10 = sp[l];
        const float s11 = sp[64 + l];
        const float s12 = sp[128 + l];
        const float s13 = sp[192 + l];
        sum1[0] += s10; sum1[1] += s11; sum1[2] += s12; sum1[3] += s13;
#pragma unroll
        for (int i = 0; i < 4; ++i) {
            const v4f q = *(const v4f*)&pp[4 * (m_[i] * 25 + n)];  // uniform b128
            float x0 = sinp(fmaf(q[0], tv0, q[1]));
            float x1 = sinp(fmaf(q[0], tv1, q[1]));
            float x2 = fmaf(q[2], x1, -x0);
            float x3 = fmaf(q[2], x2, -x1);
            acc[i][0] = fmaf(x0, s10, acc[i][0]);
            acc[i][1] = fmaf(x1, s11, acc[i][1]);
            acc[i][2] = fmaf(x2, s12, acc[i][2]);
            acc[i][3] = fmaf(x3, s13, acc[i][3]);
        }
    }

    float pw[4] = {0.f, 0.f, 0.f, 0.f};
#pragma unroll
    for (int i = 0; i < 4; ++i) {
        const v4f q3 = *(const v4f*)&pp[3000 + 4 * m_[i]];
        float y0 = sinp(fmaf(q3[0], tv0, q3[1]));
        float y1 = sinp(fmaf(q3[0], tv1, q3[1]));
        float y2 = fmaf(q3[2], y1, -y0);
        float y3 = fmaf(q3[2], y2, -y1);
        const float s20 = fmaf(0.5f, acc[i][0], 0.5f * sum1[0]);
        const float s21 = fmaf(0.5f, acc[i][1], 0.5f * sum1[1]);
        const float s22 = fmaf(0.5f, acc[i][2], 0.5f * sum1[2]);
        const float s23 = fmaf(0.5f, acc[i][3], 0.5f * sum1[3]);
        pw[0] = fmaf(fl[i] * fmaf(0.5f, y0, 0.5f), s20, pw[0]);
        pw[1] = fmaf(fl[i] * fmaf(0.5f, y1, 0.5f), s21, pw[1]);
        pw[2] = fmaf(fl[i] * fmaf(0.5f, y2, 0.5f), s22, pw[2]);
        pw[3] = fmaf(fl[i] * fmaf(0.5f, y3, 0.5f), s23, pw[3]);
    }
#pragma unroll
    for (int j = 0; j < 4; ++j)
        shp[(w * 4 + j) * 64 + l] = pw[j];
    __syncthreads();

    // wave w (w<4) handles j == w
    if (w < 4) {
        float r = 0.0f;
#pragma unroll
        for (int w2 = 0; w2 < 8; ++w2)
            r += shp[(w2 * 4 + w) * 64 + l];
        const int tt = tb + 64 * w + l;
        if (tt < T_TOTAL) out[tt] = r;
    }
}

extern "C" void kernel_launch(void* const* d_in, const int* in_sizes, int n_in,
                              void* d_out, int out_size, void* d_ws, size_t ws_size,
                              hipStream_t stream) {
    (void)in_sizes; (void)n_in; (void)d_ws; (void)ws_size; (void)out_size;
    const float* A0    = (const float*)d_in[1];
    const float* w0    = (const float*)d_in[2];
    const float* phi0  = (const float*)d_in[3];
    const float* wc0   = (const float*)d_in[4];
    const float* phic0 = (const float*)d_in[5];
    const float* w1    = (const float*)d_in[6];
    const float* phi1  = (const float*)d_in[7];
    const float* wc1   = (const float*)d_in[8];
    const float* phic1 = (const float*)d_in[9];
    const float* w2    = (const float*)d_in[10];
    const float* phi2  = (const float*)d_in[11];
    const float* wc2   = (const float*)d_in[12];
    const float* phic2 = (const float*)d_in[13];
    const float* w3    = (const float*)d_in[14];
    const float* phi3  = (const float*)d_in[15];
    const float* wc3   = (const float*)d_in[16];
    const float* phic3 = (const float*)d_in[17];

    float* out = (float*)d_out;

    hipLaunchKernelGGL(prep_kernel, dim3(6), dim3(256), 0, stream,
                       A0, w0, phi0, wc0, phic0,
                       w1, phi1, wc1, phic1,
                       w2, phi2, wc2, phic2,
                       w3, phi3, wc3, phic3);

    const int grid = (T_TOTAL + 255) / 256;   // 782
    hipLaunchKernelGGL(k_l01, dim3(grid), dim3(512), 0, stream);
    hipLaunchKernelGGL(k_l23, dim3(grid), dim3(512), 0, stream, out);
}